// Round 1
// baseline (236.268 us; speedup 1.0000x reference)
//
#include <hip/hip_runtime.h>
#include <cstdint>
#include <cstddef>

// ---- problem constants (B=1, S=2048, H=1024, NH=16, HD=64, NT=1024) ----
#define S_LEN 2048
#define H_DIM 1024
#define NTOK  1024
#define NHEAD 16
#define HDIM  64
#define NSPLIT 4

typedef __bf16 bf16;
typedef __bf16 bf16x8 __attribute__((ext_vector_type(8)));
typedef __bf16 bf16x4 __attribute__((ext_vector_type(4)));
typedef float  f32x4  __attribute__((ext_vector_type(4)));

// 0.125 (1/sqrt(HD)) * log2(e): baked into q so softmax runs in log2 domain.
#define QSCALE_LOG2E 0.18033688011112042f

static __device__ __forceinline__ f32x4 mfma16(bf16x8 a, bf16x8 b, f32x4 c) {
    return __builtin_amdgcn_mfma_f32_16x16x32_bf16(a, b, c, 0, 0, 0);
}

static __device__ __forceinline__ void async16(const void* gp, void* lp) {
    __builtin_amdgcn_global_load_lds(
        (const __attribute__((address_space(1))) void*)gp,
        (__attribute__((address_space(3))) void*)lp, 16, 0, 0);
}

static __device__ __forceinline__ float fexp2(float x) {
    return __builtin_amdgcn_exp2f(x);
}

// ---------------------------------------------------------------------------
// Merged prep: y<6 -> fp32->bf16 convert (1M elems each: x as 2 jobs + 4 key
// matrices); y>=6 -> fp32 1024x1024 -> transposed bf16 (4 val matrices).
// One launch instead of two: fewer kernel boundaries, better CU fill.
// ---------------------------------------------------------------------------
struct PrepArgs {
    const float* csrc[6];
    bf16* cdst[6];
    const float* tsrc[4];
    bf16* tdst[4];
};
__global__ __launch_bounds__(256) void prep_kernel(PrepArgs a) {
    __shared__ float t[32][33];
    if (blockIdx.y < 6) {
        const float* __restrict__ s = a.csrc[blockIdx.y];
        bf16* __restrict__ d = a.cdst[blockIdx.y];
        size_t i = ((size_t)blockIdx.x * 256 + threadIdx.x) * 4;
        f32x4 v = *(const f32x4*)&s[i];
        bf16x4 o;
        o[0] = (bf16)v[0]; o[1] = (bf16)v[1]; o[2] = (bf16)v[2]; o[3] = (bf16)v[3];
        *(bf16x4*)&d[i] = o;
    } else {
        const int z = blockIdx.y - 6;
        const float* __restrict__ in = a.tsrc[z];
        bf16* __restrict__ out = a.tdst[z];
        const int bx = (blockIdx.x & 31) * 32, by = (blockIdx.x >> 5) * 32;
        const int x = threadIdx.x & 31, y0 = threadIdx.x >> 5;
#pragma unroll
        for (int j = 0; j < 32; j += 8)
            t[y0 + j][x] = in[(size_t)(by + y0 + j) * 1024 + bx + x];
        __syncthreads();
#pragma unroll
        for (int j = 0; j < 32; j += 8)
            out[(size_t)(bx + y0 + j) * 1024 + by + x] = (bf16)t[x][y0 + j];
    }
}

// ---------------------------------------------------------------------------
// GEMM args. MODE 1: C = gelu(A B^T), atomically accumulate row sum-of-squares
// into S (must be pre-zeroed). MODE 2: C = A B^T * 32*rsqrt(S[row]) * emul;
// Ct != nullptr (z=2 only) => write V^T-layout (VtG) with baked chunk swizzle.
// ---------------------------------------------------------------------------
template <int MODE, typename OutT>
struct GemmArgs {
    const bf16* A[3];
    const bf16* B[3];
    OutT* C[3];
    float* S[3];
    bf16* Ct[3];
    float emul[3];
};

// ---------------------------------------------------------------------------
// GEMM (R8-proven): 128x64 tile, BK=64, dbuf async16 staging, XOR swizzle.
// 4 waves x (64x32). 768 blocks (z=3) = 3/CU at (256,3).
// ---------------------------------------------------------------------------
template <int MODE, typename OutT>
__global__ __launch_bounds__(256, 3) void gemm_bt(GemmArgs<MODE, OutT> args) {
    constexpr int Kd = 1024, Nd = 1024, BK = 64;
    const bf16* __restrict__ A = args.A[blockIdx.z];
    const bf16* __restrict__ B = args.B[blockIdx.z];
    OutT* __restrict__ C = args.C[blockIdx.z];
    float* __restrict__ S = args.S[blockIdx.z];
    bf16* __restrict__ Ct = args.Ct[blockIdx.z];
    const float emul = args.emul[blockIdx.z];

    __shared__ __align__(16) bf16 As[2][128 * BK];
    __shared__ __align__(16) bf16 Bs[2][64 * BK];

    const int tid = threadIdx.x;
    const int w = tid >> 6, lane = tid & 63, quad = lane >> 4, m16 = lane & 15;
    const int wm = (w >> 1) * 64, wn = (w & 1) * 32;
    const int bm = blockIdx.y * 128, bn = blockIdx.x * 64;

    const int srow = lane >> 3;
    const int sseg = ((lane & 7) ^ srow) * 8;

    auto stage = [&](int buf, int k0) {
        const bf16* Ab = A + (size_t)bm * Kd + k0;
#pragma unroll
        for (int c = 0; c < 4; ++c) {
            int chunk = w * 4 + c;
            async16(Ab + (size_t)(chunk * 8 + srow) * Kd + sseg,
                    &As[buf][chunk * 512]);
        }
        const bf16* Bb = B + (size_t)bn * Kd + k0;
#pragma unroll
        for (int c = 0; c < 2; ++c) {
            int chunk = w * 2 + c;
            async16(Bb + (size_t)(chunk * 8 + srow) * Kd + sseg,
                    &Bs[buf][chunk * 512]);
        }
    };

    f32x4 acc[4][2] = {};
    stage(0, 0);

    for (int k0 = 0; k0 < Kd; k0 += BK) {
        const int buf = (k0 >> 6) & 1;
        asm volatile("s_waitcnt vmcnt(0)" ::: "memory");
        __syncthreads();
        if (k0 + BK < Kd) stage(buf ^ 1, k0 + BK);

        bf16x8 a[2][4], b[2][2];
#pragma unroll
        for (int kc = 0; kc < 2; ++kc) {
#pragma unroll
            for (int i = 0; i < 4; ++i) {
                int row = wm + i * 16 + m16;
                a[kc][i] = *(const bf16x8*)
                    &As[buf][row * 64 + (((kc * 4 + quad) ^ (row & 7)) << 3)];
            }
#pragma unroll
            for (int j = 0; j < 2; ++j) {
                int row = wn + j * 16 + m16;
                b[kc][j] = *(const bf16x8*)
                    &Bs[buf][row * 64 + (((kc * 4 + quad) ^ (row & 7)) << 3)];
            }
        }
#pragma unroll
        for (int kc = 0; kc < 2; ++kc)
#pragma unroll
            for (int i = 0; i < 4; ++i)
#pragma unroll
                for (int j = 0; j < 2; ++j)
                    acc[i][j] = mfma16(a[kc][i], b[kc][j], acc[i][j]);
    }

    if (MODE == 1) {
        // gelu + store + fused row sum-of-squares (norm computed from f32,
        // pre-bf16-rounding -> closer to reference than separate rowscale).
        float sq[4][4] = {};
#pragma unroll
        for (int i = 0; i < 4; ++i)
#pragma unroll
            for (int j = 0; j < 2; ++j)
#pragma unroll
                for (int r = 0; r < 4; ++r) {
                    int row = bm + wm + i * 16 + quad * 4 + r;
                    int col = bn + wn + j * 16 + m16;
                    float v = acc[i][j][r];
                    v = 0.5f * v * (1.0f + erff(v * 0.70710678118654752f));
                    C[(size_t)row * Nd + col] = (OutT)v;
                    sq[i][r] += v * v;
                }
#pragma unroll
        for (int i = 0; i < 4; ++i)
#pragma unroll
            for (int r = 0; r < 4; ++r) {
                float s2 = sq[i][r];
                s2 += __shfl_xor(s2, 1);
                s2 += __shfl_xor(s2, 2);
                s2 += __shfl_xor(s2, 4);
                s2 += __shfl_xor(s2, 8);
                if (m16 == 0)
                    atomicAdd(&S[bm + wm + i * 16 + quad * 4 + r], s2);
            }
        return;
    }

    // MODE == 2: per-row scale from fused sum-of-squares
    float scl[4][4];
#pragma unroll
    for (int i = 0; i < 4; ++i)
#pragma unroll
        for (int r = 0; r < 4; ++r)
            scl[i][r] =
                32.0f * rsqrtf(S[bm + wm + i * 16 + quad * 4 + r]) * emul;

    if (Ct != nullptr) {
        // transposed + swizzle-baked VtG write: Ct[col][k] layout, chunk
        // (k&63)>>3 stored at (chunk ^ (col&7)); 4 contiguous k per lane.
#pragma unroll
        for (int i = 0; i < 4; ++i)
#pragma unroll
            for (int j = 0; j < 2; ++j) {
                int k = bm + wm + i * 16 + quad * 4;  // base of 4 contig k
                int col = bn + wn + j * 16 + m16;     // d-index (h*64+d)
                bf16x4 o4;
#pragma unroll
                for (int r = 0; r < 4; ++r)
                    o4[r] = (bf16)(acc[i][j][r] * scl[i][r]);
                int kb = k >> 6, c = (k >> 3) & 7, off = k & 7;
                int pos = ((c ^ (col & 7)) << 3) + off;
                *(bf16x4*)&Ct[(size_t)col * 2048 + kb * 64 + pos] = o4;
            }
        return;
    }

#pragma unroll
    for (int i = 0; i < 4; ++i)
#pragma unroll
        for (int j = 0; j < 2; ++j)
#pragma unroll
            for (int r = 0; r < 4; ++r) {
                int row = bm + wm + i * 16 + quad * 4 + r;
                int col = bn + wn + j * 16 + m16;
                C[(size_t)row * Nd + col] = (OutT)(acc[i][j][r] * scl[i][r]);
            }
}

// ---------------------------------------------------------------------------
// GEMM 512-thread variant for z=1 proj launches: 128x64 tile, 8 waves of
// 32x32 -> 8 waves/CU at 1 block/CU (vs 4) for latency hiding.
// ---------------------------------------------------------------------------
template <int MODE, typename OutT>
__global__ __launch_bounds__(512) void gemm_bt512(GemmArgs<MODE, OutT> args) {
    constexpr int Kd = 1024, Nd = 1024, BK = 64;
    const bf16* __restrict__ A = args.A[blockIdx.z];
    const bf16* __restrict__ B = args.B[blockIdx.z];
    OutT* __restrict__ C = args.C[blockIdx.z];
    float* __restrict__ S = args.S[blockIdx.z];
    const float emul = args.emul[blockIdx.z];

    __shared__ __align__(16) bf16 As[2][128 * BK];
    __shared__ __align__(16) bf16 Bs[2][64 * BK];

    const int tid = threadIdx.x;
    const int w = tid >> 6, lane = tid & 63, quad = lane >> 4, m16 = lane & 15;
    const int wm = (w >> 1) * 32, wn = (w & 1) * 32;
    const int bm = blockIdx.y * 128, bn = blockIdx.x * 64;

    const int srow = lane >> 3;
    const int sseg = ((lane & 7) ^ srow) * 8;

    auto stage = [&](int buf, int k0) {
        const bf16* Ab = A + (size_t)bm * Kd + k0;
#pragma unroll
        for (int c = 0; c < 2; ++c) {
            int chunk = w * 2 + c;
            async16(Ab + (size_t)(chunk * 8 + srow) * Kd + sseg,
                    &As[buf][chunk * 512]);
        }
        const bf16* Bb = B + (size_t)bn * Kd + k0;
        {
            int chunk = w;
            async16(Bb + (size_t)(chunk * 8 + srow) * Kd + sseg,
                    &Bs[buf][chunk * 512]);
        }
    };

    f32x4 acc[2][2] = {};
    stage(0, 0);

    for (int k0 = 0; k0 < Kd; k0 += BK) {
        const int buf = (k0 >> 6) & 1;
        asm volatile("s_waitcnt vmcnt(0)" ::: "memory");
        __syncthreads();
        if (k0 + BK < Kd) stage(buf ^ 1, k0 + BK);

        bf16x8 a[2][2], b[2][2];
#pragma unroll
        for (int kc = 0; kc < 2; ++kc) {
#pragma unroll
            for (int i = 0; i < 2; ++i) {
                int row = wm + i * 16 + m16;
                a[kc][i] = *(const bf16x8*)
                    &As[buf][row * 64 + (((kc * 4 + quad) ^ (row & 7)) << 3)];
            }
#pragma unroll
            for (int j = 0; j < 2; ++j) {
                int row = wn + j * 16 + m16;
                b[kc][j] = *(const bf16x8*)
                    &Bs[buf][row * 64 + (((kc * 4 + quad) ^ (row & 7)) << 3)];
            }
        }
#pragma unroll
        for (int kc = 0; kc < 2; ++kc)
#pragma unroll
            for (int i = 0; i < 2; ++i)
#pragma unroll
                for (int j = 0; j < 2; ++j)
                    acc[i][j] = mfma16(a[kc][i], b[kc][j], acc[i][j]);
    }

    if (MODE == 1) {
        float sq[2][4] = {};
#pragma unroll
        for (int i = 0; i < 2; ++i)
#pragma unroll
            for (int j = 0; j < 2; ++j)
#pragma unroll
                for (int r = 0; r < 4; ++r) {
                    int row = bm + wm + i * 16 + quad * 4 + r;
                    int col = bn + wn + j * 16 + m16;
                    float v = acc[i][j][r];
                    v = 0.5f * v * (1.0f + erff(v * 0.70710678118654752f));
                    C[(size_t)row * Nd + col] = (OutT)v;
                    sq[i][r] += v * v;
                }
#pragma unroll
        for (int i = 0; i < 2; ++i)
#pragma unroll
            for (int r = 0; r < 4; ++r) {
                float s2 = sq[i][r];
                s2 += __shfl_xor(s2, 1);
                s2 += __shfl_xor(s2, 2);
                s2 += __shfl_xor(s2, 4);
                s2 += __shfl_xor(s2, 8);
                if (m16 == 0)
                    atomicAdd(&S[bm + wm + i * 16 + quad * 4 + r], s2);
            }
        return;
    }

    float scl[2][4];
#pragma unroll
    for (int i = 0; i < 2; ++i)
#pragma unroll
        for (int r = 0; r < 4; ++r)
            scl[i][r] =
                32.0f * rsqrtf(S[bm + wm + i * 16 + quad * 4 + r]) * emul;

#pragma unroll
    for (int i = 0; i < 2; ++i)
#pragma unroll
        for (int j = 0; j < 2; ++j)
#pragma unroll
            for (int r = 0; r < 4; ++r) {
                int row = bm + wm + i * 16 + quad * 4 + r;
                int col = bn + wn + j * 16 + m16;
                C[(size_t)row * Nd + col] = (OutT)(acc[i][j][r] * scl[i][r]);
            }
}

// ---------------------------------------------------------------------------
// Causal flash attention — S^T formulation (R8 body) + XCD-aware decode:
// 1-D grid of 1024; xcd = bid&7 (dispatch round-robin heuristic) owns 2
// heads -> per-XCD working set Q+K+Vt ~1.5 MB fits 4 MB L2, so critical-path
// K loads become L2 hits. Paired q-tiles, NSPLIT=4, (256,4): no spill.
// Softmax in log2 domain: 0.125*log2e baked into q by gemm2's epilogue, so
// p = exp2(s - m) on native v_exp_f32, no per-element scale multiply.
// Defer-max (T13): skip O-rescale when max growth <= 11.5 (= 8 nats).
// ---------------------------------------------------------------------------
struct FlashArgs {
    const bf16* Q;
    const bf16* K;
    const bf16* VtG;
    bf16* op[NSPLIT];
    float* ml;
};

__global__ __launch_bounds__(256, 4) void flash_kernel(FlashArgs fa) {
    const int bid = blockIdx.x;
    const int idx = bid >> 3;
    const int h = (bid & 7) * 2 + (idx & 1);
    const int pr = (idx >> 1) & 15;
    const int s = idx >> 5;
    const int tid = threadIdx.x;
    const int w = tid >> 6, lane = tid & 63, quad = lane >> 4, m16 = lane & 15;
    const int hOff = h * HDIM;

    __shared__ __align__(16) bf16 Vs[64 * 64];    // V^T tile (baked swizzle)
    __shared__ __align__(16) bf16 Pw[4][16][72];  // per-wave P: [qrow][kcol]

    const int vrow = tid >> 3, vchunk = (tid & 7) * 8;
    const bf16* VtH = fa.VtG + (size_t)hOff * 2048;
    bf16* __restrict__ Opart = fa.op[s];

#pragma unroll
    for (int ti = 0; ti < 2; ++ti) {
        const int qt = ti ? 31 - pr : pr;
        const int qRow = qt * 64 + w * 16 + m16;  // this lane's q-row
        bf16x8 bq[2];
        bq[0] = *(const bf16x8*)&fa.Q[(size_t)qRow * H_DIM + hOff + quad * 8];
        bq[1] = *(const bf16x8*)&fa.Q[(size_t)qRow * H_DIM + hOff + 32 + quad * 8];

        f32x4 oacc[4] = {};   // O^T C-layout: [d-subtile jd]; row=d, col=qrow
        float m_i = -1e30f, l_i = 0.0f;

        for (int kt = s; kt <= qt; kt += NSPLIT) {
            const int k0 = kt * 64;
            const bool diag = (kt == qt);
            __syncthreads();  // prior PV reads of Vs complete
#pragma unroll
            for (int p = 0; p < 2; ++p) {
                int d = vrow + p * 32;
                async16(VtH + (size_t)d * 2048 + k0 + vchunk,
                        &Vs[d * 64 + vchunk]);
            }
            // S^T = K Q^T   (scores already in log2 domain via baked q-scale)
            f32x4 sacc[4] = {};
            __builtin_amdgcn_s_setprio(1);
#pragma unroll
            for (int ks = 0; ks < 2; ++ks)
#pragma unroll
                for (int j = 0; j < 4; ++j) {
                    bf16x8 ak = *(const bf16x8*)
                        &fa.K[(size_t)(k0 + j * 16 + m16) * H_DIM + hOff +
                              ks * 32 + quad * 8];
                    sacc[j] = mfma16(ak, bq[ks], sacc[j]);
                }
            __builtin_amdgcn_s_setprio(0);
            // online softmax (log2 domain): each lane owns q-row m16
            float sv[4][4];
            float mx = -1e30f;
#pragma unroll
            for (int j = 0; j < 4; ++j)
#pragma unroll
                for (int rr = 0; rr < 4; ++rr) {
                    float sc = sacc[j][rr];
                    int kcol = k0 + j * 16 + quad * 4 + rr;
                    if (diag && kcol > qRow) sc = -1e30f;
                    sv[j][rr] = sc;
                    mx = fmaxf(mx, sc);
                }
            mx = fmaxf(mx, __shfl_xor(mx, 16));
            mx = fmaxf(mx, __shfl_xor(mx, 32));
            // defer-max: only rescale when the running max grew materially
            if (!__all(mx - m_i <= 11.5f)) {
                float mnew = fmaxf(m_i, mx);
                float alpha = fexp2(m_i - mnew);
                l_i *= alpha;
#pragma unroll
                for (int jd = 0; jd < 4; ++jd)
#pragma unroll
                    for (int rr = 0; rr < 4; ++rr) oacc[jd][rr] *= alpha;
                m_i = mnew;
            }
            float ls = 0.0f;
#pragma unroll
            for (int j = 0; j < 4; ++j) {
                bf16x4 pk;
#pragma unroll
                for (int rr = 0; rr < 4; ++rr) {
                    float p = fexp2(sv[j][rr] - m_i);
                    ls += p;
                    pk[rr] = (bf16)p;
                }
                *(bf16x4*)&Pw[w][m16][j * 16 + quad * 4] = pk;
            }
            ls += __shfl_xor(ls, 16);
            ls += __shfl_xor(ls, 32);
            l_i += ls;
            asm volatile("s_waitcnt vmcnt(0)" ::: "memory");
            __syncthreads();  // V staged; Pw ordered by barrier's lgkm drain
            // O^T += V^T P^T
            __builtin_amdgcn_s_setprio(1);
#pragma unroll
            for (int ks = 0; ks < 2; ++ks) {
                bf16x8 bp = *(const bf16x8*)&Pw[w][m16][ks * 32 + quad * 8];
#pragma unroll
                for (int jd = 0; jd < 4; ++jd) {
                    int d = jd * 16 + m16;
                    bf16x8 av = *(const bf16x8*)
                        &Vs[d * 64 + (((ks * 4 + quad) ^ (d & 7)) << 3)];
                    oacc[jd] = mfma16(av, bp, oacc[jd]);
                }
            }
            __builtin_amdgcn_s_setprio(0);
        }
#pragma unroll
        for (int jd = 0; jd < 4; ++jd) {
            bf16x4 o4;
#pragma unroll
            for (int rr = 0; rr < 4; ++rr) o4[rr] = (bf16)oacc[jd][rr];
            *(bf16x4*)&Opart[(size_t)qRow * 1024 + hOff + jd * 16 + quad * 4] = o4;
        }
        if (quad == 0) {
            float* p = fa.ml + ((size_t)(s * 2048 + qRow) * 16 + h) * 2;
            p[0] = m_i;   // log2 domain
            p[1] = l_i;
        }
    }
}

// ---------------------------------------------------------------------------
// Combine the split partials: one wave per (row, head), lane = d.
// m/l are in log2 domain -> exp2.
// ---------------------------------------------------------------------------
struct CombArgs {
    const bf16* op[NSPLIT];
    const float* ml;
    bf16* ctx;
};
__global__ __launch_bounds__(256) void combine_kernel(CombArgs ca) {
    const int unit = blockIdx.x * 4 + (threadIdx.x >> 6);
    const int row = unit >> 4, h = unit & 15;
    const int d = threadIdx.x & 63;
    float mv[NSPLIT], lv[NSPLIT], M = -1e30f;
#pragma unroll
    for (int s2 = 0; s2 < NSPLIT; ++s2) {
        const float* p = ca.ml + ((size_t)(s2 * 2048 + row) * 16 + h) * 2;
        mv[s2] = p[0];
        lv[s2] = p[1];
        M = fmaxf(M, mv[s2]);
    }
    float num = 0.0f, den = 0.0f;
#pragma unroll
    for (int s2 = 0; s2 < NSPLIT; ++s2) {
        float e = fexp2(mv[s2] - M);
        den += lv[s2] * e;
        num += e * (float)ca.op[s2][(size_t)row * 1024 + h * 64 + d];
    }
    ca.ctx[(size_t)row * 1024 + h * 64 + d] = (bf16)(num / den);
}

// ---------------------------------------------------------------------------
// Orchestration. Inputs/outputs FLOAT32 per the reference.
// ws layout (40 MB, phase-aliased):
//   0..4M    xb -> qb                16..24M  kb16[0..3] (kb16[3]=proj key)
//   4..16M   g3[0..2] -> Opart s0-2  24..32M  vT16[0..3] (vT16[3]=proj val)
//   16..20M  kb16[0,1] (dead) -> Opart s3
//   20..22M  kb16[2]   (dead) -> ml (1M)
//   32..36M  kbuf -> ctx
//   36..40M  VtG (written by gemm2 z=2 epilogue) -> SSp (8K, post-flash)
//   projg aliases 4..8M after combine.
// SSq (3x2048 f32 sum-of-squares) lives in d_out (untouched until p2).
// ---------------------------------------------------------------------------
extern "C" void kernel_launch(void* const* d_in, const int* in_sizes, int n_in,
                              void* d_out, int out_size, void* d_ws,
                              size_t ws_size, hipStream_t stream) {
    const float* x = (const float*)d_in[0];
    const float* keysF[4] = {(const float*)d_in[1], (const float*)d_in[3],
                             (const float*)d_in[5], (const float*)d_in[7]};
    const float* valsF[4] = {(const float*)d_in[2], (const float*)d_in[4],
                             (const float*)d_in[6], (const float*)d_in[8]};
    float* out = (float*)d_out;

    char* ws = (char*)d_ws;
    bf16* xb = (bf16*)(ws);
    bf16* g3[3];
    for (int i = 0; i < 3; ++i) g3[i] = (bf16*)(ws + (4ull << 20) + (size_t)i * (4ull << 20));
    bf16* kb16[4], *vT16[4];
    for (int i = 0; i < 4; ++i) {
        kb16[i] = (bf16*)(ws + (16ull << 20) + (size_t)i * (2ull << 20));
        vT16[i] = (bf16*)(ws + (24ull << 20) + (size_t)i * (2ull << 20));
    }
    bf16* qb    = (bf16*)(ws);
    bf16* kbuf  = (bf16*)(ws + (32ull << 20));
    float* mlbuf = (float*)(ws + (20ull << 20));
    bf16* VtG   = (bf16*)(ws + (36ull << 20));
    bf16* ctx   = (bf16*)(ws + (32ull << 20));
    bf16* projg = (bf16*)(ws + (4ull << 20));

    float* SSq = (float*)d_out;               // 3x2048 f32 (out: dead til p2)
    float* SSp = (float*)(ws + (36ull << 20)); // 2048 f32 (VtG dead post-flash)

    bf16* opart[NSPLIT];
    for (int i = 0; i < NSPLIT; ++i)
        opart[i] = (bf16*)(ws + (4ull << 20) + (size_t)i * (4ull << 20));

    // 0. zero QKV sum-of-squares accumulators (capture-safe async memset)
    hipMemsetAsync(SSq, 0, 3 * 2048 * sizeof(float), stream);

    // 1. merged prep: convert x + 4 keys; transpose+convert 4 vals
    PrepArgs pa;
    pa.csrc[0] = x;             pa.cdst[0] = xb;
    pa.csrc[1] = x + (1 << 20); pa.cdst[1] = xb + (1 << 20);
    for (int i = 0; i < 4; ++i) { pa.csrc[2 + i] = keysF[i]; pa.cdst[2 + i] = kb16[i]; }
    for (int i = 0; i < 4; ++i) { pa.tsrc[i] = valsF[i]; pa.tdst[i] = vT16[i]; }
    prep_kernel<<<dim3(1024, 10), 256, 0, stream>>>(pa);

    // 2. batched QKV: g = gelu(x @ key^T), fused row sum-of-squares -> SSq
    GemmArgs<1, bf16> g1;
    for (int z = 0; z < 3; ++z) {
        g1.A[z] = xb; g1.B[z] = kb16[z]; g1.C[z] = g3[z];
        g1.S[z] = SSq + z * 2048; g1.Ct[z] = nullptr; g1.emul[z] = 1.0f;
    }
    gemm_bt<1, bf16><<<dim3(16, 16, 3), 256, 0, stream>>>(g1);

    // 3. batched: q (with 0.125*log2e baked in), k row-major; V written
    //    directly transposed+swizzled (VtG). Scale = 32*rsqrt(SSq[row]).
    GemmArgs<2, bf16> g2;
    bf16* qkv[3] = {qb, kbuf, qb /*unused for z=2*/};
    for (int z = 0; z < 3; ++z) {
        g2.A[z] = g3[z]; g2.B[z] = vT16[z]; g2.C[z] = qkv[z];
        g2.S[z] = SSq + z * 2048;
        g2.Ct[z] = (z == 2) ? VtG : nullptr;
        g2.emul[z] = (z == 0) ? QSCALE_LOG2E : 1.0f;
    }
    gemm_bt<2, bf16><<<dim3(16, 16, 3), 256, 0, stream>>>(g2);

    // 4. flash attention (S^T form, XCD-aware 1-D grid, 4-way split)
    FlashArgs fla;
    fla.Q = qb; fla.K = kbuf; fla.VtG = VtG; fla.ml = mlbuf;
    for (int i = 0; i < NSPLIT; ++i) fla.op[i] = opart[i];
    flash_kernel<<<dim3(1024), 256, 0, stream>>>(fla);

    // 5. zero proj sum-of-squares (VtG region is dead once flash completes)
    hipMemsetAsync(SSp, 0, 2048 * sizeof(float), stream);

    // 6. combine split partials -> ctx
    CombArgs cba;
    for (int i = 0; i < NSPLIT; ++i) cba.op[i] = opart[i];
    cba.ml = mlbuf; cba.ctx = ctx;
    combine_kernel<<<dim3(8192), 256, 0, stream>>>(cba);

    // 7-8. output projection pattention (512-thread GEMMs, 8 waves/CU)
    GemmArgs<1, bf16> p1;
    for (int z = 0; z < 3; ++z) {
        p1.A[z] = ctx; p1.B[z] = kb16[3]; p1.C[z] = projg;
        p1.S[z] = SSp; p1.Ct[z] = nullptr; p1.emul[z] = 1.0f;
    }
    gemm_bt512<1, bf16><<<dim3(16, 16, 1), 512, 0, stream>>>(p1);

    GemmArgs<2, float> p2;
    for (int z = 0; z < 3; ++z) {
        p2.A[z] = projg; p2.B[z] = vT16[3]; p2.C[z] = out;
        p2.S[z] = SSp; p2.Ct[z] = nullptr; p2.emul[z] = 1.0f;
    }
    gemm_bt512<2, float><<<dim3(16, 16, 1), 512, 0, stream>>>(p2);
}